// Round 2
// baseline (13902.475 us; speedup 1.0000x reference)
//
#include <hip/hip_runtime.h>
#include <math.h>

// ---------------- problem dims ----------------
#define E_DIM 512     // embedding dim
#define H_DIM 2048    // hidden
#define G_DIM 8192    // 4*H
#define B_DIM 32      // batch
#define T_DIM 128     // target time
#define S_DIM 128     // source time
#define ENC2  1024    // 2*encoder_hidden
#define SI_DIM 1536   // E + 2*enc (static input)

// ---------------- workspace layout (bytes) ----------------
// whh_hi bf16 [8192][2048] @ 0          (33554432)
// whh_lo bf16 [8192][2048] @ 33554432   (33554432)
// wih_hi bf16 [8192][512]  @ 67108864   (8388608)
// wih_lo bf16 [8192][512]  @ 75497472   (8388608)
// x_hi   bf16 [4096][512]  @ 83886080   (4194304)
// x_lo   bf16 [4096][512]  @ 88080384   (4194304)
// sg     f32  [32][8192]   @ 92274688   (1048576)
// si     f32  [32][1536]   @ 93323264   (196608)
// hb_hi  bf16 2x[32][2048] @ 93519872   (262144)
// hb_lo  bf16 2x[32][2048] @ 93782016   (262144)
// cb     f32  [32][2048]   @ 94044160   (262144)
// total ~94.3 MB (round-0's 115 MB worked)

typedef __bf16 bf16_t;
typedef bf16_t bf16x8 __attribute__((ext_vector_type(8)));
typedef float f32x4 __attribute__((ext_vector_type(4)));

union FragAB { bf16x8 v; uint2 u2[2]; };

#define LOADFRAG(dst, base) do { const uint2* _p = (const uint2*)(base); \
    (dst).u2[0] = _p[0]; (dst).u2[1] = _p[4]; } while (0)

__device__ __forceinline__ unsigned short f2bf(float x) {
    unsigned u = __float_as_uint(x);
    u += 0x7FFFu + ((u >> 16) & 1u);   // RNE
    return (unsigned short)(u >> 16);
}
__device__ __forceinline__ float bf2f(unsigned short s) {
    return __uint_as_float(((unsigned)s) << 16);
}
__device__ __forceinline__ f32x4 mfma16(bf16x8 a, bf16x8 b, f32x4 c) {
    return __builtin_amdgcn_mfma_f32_16x16x32_bf16(a, b, c, 0, 0, 0);
}
__device__ __forceinline__ float sigf(float x) { return 1.f / (1.f + expf(-x)); }

// ---- prep: context max-pool, lang embed gather, h0 split / c0 copy ----
__global__ void k_prep(const float* __restrict__ enc_outs, const float* __restrict__ embed,
                       const int* __restrict__ langs, const float* __restrict__ h0,
                       const float* __restrict__ c0, float* __restrict__ si,
                       unsigned short* __restrict__ hhi, unsigned short* __restrict__ hlo,
                       float* __restrict__ cb) {
    int tid = blockIdx.x * blockDim.x + threadIdx.x;
    int np = gridDim.x * blockDim.x;
    for (int i = tid; i < B_DIM * ENC2; i += np) {        // context = max over S
        int b = i >> 10, e = i & 1023;
        float m = -3.4e38f;
        for (int s = 0; s < S_DIM; ++s)
            m = fmaxf(m, enc_outs[(s * B_DIM + b) * ENC2 + e]);
        si[b * SI_DIM + E_DIM + e] = m;
    }
    for (int i = tid; i < B_DIM * E_DIM; i += np) {       // lang embedding
        int b = i >> 9, e = i & 511;
        si[b * SI_DIM + e] = embed[(long)langs[b] * E_DIM + e];
    }
    for (int i = tid; i < B_DIM * H_DIM; i += np) {       // h0 split / c0 copy
        float h = h0[i];
        unsigned short hi = f2bf(h);
        hhi[i] = hi;
        hlo[i] = f2bf(h - bf2f(hi));
        cb[i] = c0[i];
    }
}

// ---- static gate bias: sg[b][g] = b_ih[g]+b_hh[g] + si[b]·W_ih[g][512:2048] (fp32) ----
__global__ __launch_bounds__(256) void k_sgates(const float* __restrict__ W_ih,
        const float* __restrict__ b_ih, const float* __restrict__ b_hh,
        const float* __restrict__ si, float* __restrict__ sg) {
    __shared__ float wl[8][SI_DIM];
    int g0 = blockIdx.x * 8;
    for (int i = threadIdx.x; i < 8 * SI_DIM; i += 256) {
        int r = i / SI_DIM, e = i - r * SI_DIM;
        wl[r][e] = W_ih[(long)(g0 + r) * 2048 + E_DIM + e];
    }
    __syncthreads();
    int gl = threadIdx.x >> 5, b = threadIdx.x & 31;
    const float4* sib4 = (const float4*)(si + b * SI_DIM);
    float a0 = 0.f, a1 = 0.f, a2 = 0.f, a3 = 0.f;
    for (int e4 = 0; e4 < SI_DIM / 4; ++e4) {
        float4 s4 = sib4[e4];
        const float4 w4 = *(const float4*)&wl[gl][e4 * 4];
        a0 = fmaf(s4.x, w4.x, a0); a1 = fmaf(s4.y, w4.y, a1);
        a2 = fmaf(s4.z, w4.z, a2); a3 = fmaf(s4.w, w4.w, a3);
    }
    int g = g0 + gl;
    sg[b * G_DIM + g] = (a0 + a1) + (a2 + a3) + b_ih[g] + b_hh[g];
}

// ---- split W_hh -> hi/lo bf16 (row-major [8192][2048]) ----
__global__ void k_split_whh(const float* __restrict__ W, unsigned short* __restrict__ hi,
                            unsigned short* __restrict__ lo) {
    int n4 = G_DIM * H_DIM / 4;
    for (int i = blockIdx.x * blockDim.x + threadIdx.x; i < n4; i += gridDim.x * blockDim.x) {
        float4 v = ((const float4*)W)[i];
        ushort4 h, l;
        h.x = f2bf(v.x); l.x = f2bf(v.x - bf2f(h.x));
        h.y = f2bf(v.y); l.y = f2bf(v.y - bf2f(h.y));
        h.z = f2bf(v.z); l.z = f2bf(v.z - bf2f(h.z));
        h.w = f2bf(v.w); l.w = f2bf(v.w - bf2f(h.w));
        ((ushort4*)hi)[i] = h; ((ushort4*)lo)[i] = l;
    }
}

// ---- split W_ih[:, :512] -> hi/lo bf16 [8192][512] ----
__global__ void k_split_wih(const float* __restrict__ W, unsigned short* __restrict__ hi,
                            unsigned short* __restrict__ lo) {
    int n4 = G_DIM * E_DIM / 4;
    for (int i = blockIdx.x * blockDim.x + threadIdx.x; i < n4; i += gridDim.x * blockDim.x) {
        int g = i >> 7, e4 = i & 127;
        float4 v = *(const float4*)(W + (long)g * 2048 + e4 * 4);
        ushort4 h, l;
        h.x = f2bf(v.x); l.x = f2bf(v.x - bf2f(h.x));
        h.y = f2bf(v.y); l.y = f2bf(v.y - bf2f(h.y));
        h.z = f2bf(v.z); l.z = f2bf(v.z - bf2f(h.z));
        h.w = f2bf(v.w); l.w = f2bf(v.w - bf2f(h.w));
        ((ushort4*)hi)[i] = h; ((ushort4*)lo)[i] = l;
    }
}

// ---- gather token embeddings -> x hi/lo [T*B][512], row r = t*32+b ----
__global__ void k_gather_x(const float* __restrict__ embed, const int* __restrict__ tok,
                           unsigned short* __restrict__ xhi, unsigned short* __restrict__ xlo) {
    int r = blockIdx.x;
    int t = r >> 5, b = r & 31;
    long row = tok[b * T_DIM + t];
    const float4* src = (const float4*)(embed + row * E_DIM);
    ushort4* dh = (ushort4*)(xhi + (long)r * E_DIM);
    ushort4* dl = (ushort4*)(xlo + (long)r * E_DIM);
    for (int i = threadIdx.x; i < E_DIM / 4; i += blockDim.x) {
        float4 v = src[i];
        ushort4 h, l;
        h.x = f2bf(v.x); l.x = f2bf(v.x - bf2f(h.x));
        h.y = f2bf(v.y); l.y = f2bf(v.y - bf2f(h.y));
        h.z = f2bf(v.z); l.z = f2bf(v.z - bf2f(h.z));
        h.w = f2bf(v.w); l.w = f2bf(v.w - bf2f(h.w));
        dh[i] = h; dl[i] = l;
    }
}

// ---- one LSTM step (split-bf16): block owns 16 hidden units; wave q = gate q ----
// gates[b][g] = sg[b][g] + h·W_hh[g,:] + x_t·W_ih[g,:512]  (each product in bf16x2)
__global__ __launch_bounds__(256) void k_step(
        const unsigned short* __restrict__ hhi, const unsigned short* __restrict__ hlo,
        const unsigned short* __restrict__ whh_hi, const unsigned short* __restrict__ whh_lo,
        const unsigned short* __restrict__ wih_hi, const unsigned short* __restrict__ wih_lo,
        const unsigned short* __restrict__ xhi, const unsigned short* __restrict__ xlo,
        const float* __restrict__ sg, float* __restrict__ cb,
        unsigned short* __restrict__ hhi_o, unsigned short* __restrict__ hlo_o,
        float* __restrict__ out_t, int t) {
    __shared__ float gl[4][B_DIM][16];
    int l = threadIdx.x & 63;
    int q = threadIdx.x >> 6;          // gate index: 0=i 1=f 2=g 3=o
    int j0 = blockIdx.x * 16;          // hidden-unit base
    int lr = l & 15, lg = l >> 4;
    int gcol = q * H_DIM + j0 + lr;    // gate column in [0, 8192)
    f32x4 acc0 = {}, acc1 = {};

    // recurrent term: K = 2048
    {
        const unsigned short* ah0 = hhi + lr * H_DIM + 4 * lg;
        const unsigned short* al0 = hlo + lr * H_DIM + 4 * lg;
        const unsigned short* bh  = whh_hi + (long)gcol * H_DIM + 4 * lg;
        const unsigned short* bl  = whh_lo + (long)gcol * H_DIM + 4 * lg;
        #pragma unroll 2
        for (int k0 = 0; k0 < H_DIM; k0 += 32) {
            FragAB Ah0, Ah1, Al0, Al1, Bh, Bl;
            LOADFRAG(Ah0, ah0 + k0);
            LOADFRAG(Ah1, ah0 + 16 * H_DIM + k0);
            LOADFRAG(Al0, al0 + k0);
            LOADFRAG(Al1, al0 + 16 * H_DIM + k0);
            LOADFRAG(Bh,  bh + k0);
            LOADFRAG(Bl,  bl + k0);
            acc0 = mfma16(Ah0.v, Bh.v, acc0);
            acc1 = mfma16(Ah1.v, Bh.v, acc1);
            acc0 = mfma16(Ah0.v, Bl.v, acc0);
            acc1 = mfma16(Ah1.v, Bl.v, acc1);
            acc0 = mfma16(Al0.v, Bh.v, acc0);
            acc1 = mfma16(Al1.v, Bh.v, acc1);
        }
    }
    // input term: K = 512, A rows are x[t*32 + b]
    {
        const unsigned short* ah0 = xhi + (long)(t * B_DIM + lr) * E_DIM + 4 * lg;
        const unsigned short* al0 = xlo + (long)(t * B_DIM + lr) * E_DIM + 4 * lg;
        const unsigned short* bh  = wih_hi + (long)gcol * E_DIM + 4 * lg;
        const unsigned short* bl  = wih_lo + (long)gcol * E_DIM + 4 * lg;
        #pragma unroll 2
        for (int k0 = 0; k0 < E_DIM; k0 += 32) {
            FragAB Ah0, Ah1, Al0, Al1, Bh, Bl;
            LOADFRAG(Ah0, ah0 + k0);
            LOADFRAG(Ah1, ah0 + 16 * E_DIM + k0);
            LOADFRAG(Al0, al0 + k0);
            LOADFRAG(Al1, al0 + 16 * E_DIM + k0);
            LOADFRAG(Bh,  bh + k0);
            LOADFRAG(Bl,  bl + k0);
            acc0 = mfma16(Ah0.v, Bh.v, acc0);
            acc1 = mfma16(Ah1.v, Bh.v, acc1);
            acc0 = mfma16(Ah0.v, Bl.v, acc0);
            acc1 = mfma16(Ah1.v, Bl.v, acc1);
            acc0 = mfma16(Al0.v, Bh.v, acc0);
            acc1 = mfma16(Al1.v, Bh.v, acc1);
        }
    }

    // C/D layout (verified): col = lane&15, row = (lane>>4)*4 + reg
    #pragma unroll
    for (int fm = 0; fm < 2; ++fm) {
        #pragma unroll
        for (int r = 0; r < 4; ++r) {
            int b = fm * 16 + lg * 4 + r;
            gl[q][b][lr] = (fm ? acc1[r] : acc0[r]) + sg[b * G_DIM + gcol];
        }
    }
    __syncthreads();

    for (int cell = threadIdx.x; cell < B_DIM * 16; cell += 256) {
        int b = cell >> 4, n = cell & 15;
        int j = j0 + n;
        float iv = gl[0][b][n], fv = gl[1][b][n], gv = gl[2][b][n], ov = gl[3][b][n];
        float c_old = cb[b * H_DIM + j];
        float cn = sigf(fv) * c_old + sigf(iv) * tanhf(gv);
        float hn = sigf(ov) * tanhf(cn);
        cb[b * H_DIM + j] = cn;
        unsigned short hi = f2bf(hn);
        hhi_o[b * H_DIM + j] = hi;
        hlo_o[b * H_DIM + j] = f2bf(hn - bf2f(hi));
        out_t[b * H_DIM + j] = hn;
    }
}

extern "C" void kernel_launch(void* const* d_in, const int* in_sizes, int n_in,
                              void* d_out, int out_size, void* d_ws, size_t ws_size,
                              hipStream_t stream) {
    const float* embed    = (const float*)d_in[0];
    const float* enc_outs = (const float*)d_in[1];
    const float* h0       = (const float*)d_in[2];
    const float* c0       = (const float*)d_in[3];
    const float* W_ih     = (const float*)d_in[4];
    const float* W_hh     = (const float*)d_in[5];
    const float* b_ih     = (const float*)d_in[6];
    const float* b_hh     = (const float*)d_in[7];
    const int*   tok      = (const int*)d_in[8];
    const int*   langs    = (const int*)d_in[9];
    float* out = (float*)d_out;

    char* ws = (char*)d_ws;
    unsigned short* whh_hi = (unsigned short*)(ws + 0);
    unsigned short* whh_lo = (unsigned short*)(ws + 33554432);
    unsigned short* wih_hi = (unsigned short*)(ws + 67108864);
    unsigned short* wih_lo = (unsigned short*)(ws + 75497472);
    unsigned short* x_hi   = (unsigned short*)(ws + 83886080);
    unsigned short* x_lo   = (unsigned short*)(ws + 88080384);
    float* sg = (float*)(ws + 92274688);
    float* si = (float*)(ws + 93323264);
    unsigned short* hb_hi = (unsigned short*)(ws + 93519872);
    unsigned short* hb_lo = (unsigned short*)(ws + 93782016);
    float* cb = (float*)(ws + 94044160);

    hipLaunchKernelGGL(k_prep, dim3(512), dim3(256), 0, stream,
                       enc_outs, embed, langs, h0, c0, si, hb_hi, hb_lo, cb);
    hipLaunchKernelGGL(k_sgates, dim3(G_DIM / 8), dim3(256), 0, stream,
                       W_ih, b_ih, b_hh, si, sg);
    hipLaunchKernelGGL(k_split_whh, dim3(4096), dim3(256), 0, stream, W_hh, whh_hi, whh_lo);
    hipLaunchKernelGGL(k_split_wih, dim3(1024), dim3(256), 0, stream, W_ih, wih_hi, wih_lo);
    hipLaunchKernelGGL(k_gather_x, dim3(T_DIM * B_DIM), dim3(128), 0, stream,
                       embed, tok, x_hi, x_lo);

    const int HB = B_DIM * H_DIM;   // elements per h buffer
    for (int t = 0; t < T_DIM; ++t) {
        int cur = t & 1, nxt = cur ^ 1;
        hipLaunchKernelGGL(k_step, dim3(H_DIM / 16), dim3(256), 0, stream,
                           hb_hi + cur * HB, hb_lo + cur * HB,
                           whh_hi, whh_lo, wih_hi, wih_lo, x_hi, x_lo,
                           sg, cb,
                           hb_hi + nxt * HB, hb_lo + nxt * HB,
                           out + (long)t * HB, t);
    }
}

// Round 3
// 9452.994 us; speedup vs baseline: 1.4707x; 1.4707x over previous
//
#include <hip/hip_runtime.h>
#include <math.h>

// ---------------- problem dims ----------------
#define E_DIM 512     // embedding dim
#define H_DIM 2048    // hidden
#define G_DIM 8192    // 4*H
#define B_DIM 32      // batch
#define T_DIM 128     // target time
#define S_DIM 128     // source time
#define ENC2  1024    // 2*encoder_hidden
#define SI_DIM 1536   // E + 2*enc (static input)

#define NBLK 256      // persistent blocks (1 per CU)
#define NTHR 512      // 8 waves
#define JT   8        // hidden cols per block
#define KHW  (H_DIM/8)   // 256: W_hh K-slice per wave
#define KXW  (E_DIM/8)   // 64:  W_ih K-slice per wave
#define ITH  (KHW/32)    // 8 k0-iters (whh)
#define ITX  (KXW/32)    // 2 k0-iters (wih)
#define HB   (B_DIM*H_DIM)   // 65536 elements per h buffer

// ---------------- workspace layout (bytes) ----------------
// x_hi  bf16 [4096][512] @ 0        (4194304)
// x_lo  bf16 [4096][512] @ 4194304  (4194304)
// hb_hi bf16 2x[32][2048] @ 8388608 (262144)
// hb_lo bf16 2x[32][2048] @ 8650752 (262144)
// si    f32  [32][1536]  @ 8912896  (196608)
// bar   u32              @ 9109504
// total ~9.1 MB

typedef __bf16 bf16_t;
typedef bf16_t bf16x8 __attribute__((ext_vector_type(8)));
typedef float f32x4 __attribute__((ext_vector_type(4)));

union FragAB { bf16x8 v; uint2 u2[2]; unsigned short s[8]; };

#define LOADFRAG(dst, base) do { const uint2* _p = (const uint2*)(base); \
    (dst).u2[0] = _p[0]; (dst).u2[1] = _p[4]; } while (0)

__device__ __forceinline__ unsigned short f2bf(float x) {
    unsigned u = __float_as_uint(x);
    u += 0x7FFFu + ((u >> 16) & 1u);   // RNE
    return (unsigned short)(u >> 16);
}
__device__ __forceinline__ float bf2f(unsigned short s) {
    return __uint_as_float(((unsigned)s) << 16);
}
__device__ __forceinline__ f32x4 mfma16(bf16x8 a, bf16x8 b, f32x4 c) {
    return __builtin_amdgcn_mfma_f32_16x16x32_bf16(a, b, c, 0, 0, 0);
}
__device__ __forceinline__ float sigf(float x) { return 1.f / (1.f + expf(-x)); }

// pack 8 consecutive-k fp32 W elements (two float4: +0 and +16 elems) into hi/lo bf16 frags
__device__ __forceinline__ void packW(const float* src, FragAB& hi, FragAB& lo) {
    float4 w0 = *(const float4*)src;
    float4 w1 = *(const float4*)(src + 16);
    float v[8] = {w0.x, w0.y, w0.z, w0.w, w1.x, w1.y, w1.z, w1.w};
    #pragma unroll
    for (int j = 0; j < 8; ++j) {
        unsigned short h = f2bf(v[j]);
        hi.s[j] = h;
        lo.s[j] = f2bf(v[j] - bf2f(h));
    }
}

// ---- prep: context max-pool, lang embed, h0 split, barrier reset ----
__global__ void k_prep(const float* __restrict__ enc_outs, const float* __restrict__ embed,
                       const int* __restrict__ langs, const float* __restrict__ h0,
                       float* __restrict__ si, unsigned short* __restrict__ hhi,
                       unsigned short* __restrict__ hlo, unsigned int* __restrict__ bar) {
    int tid = blockIdx.x * blockDim.x + threadIdx.x;
    int np = gridDim.x * blockDim.x;
    if (tid == 0)
        __hip_atomic_store(bar, 0u, __ATOMIC_RELEASE, __HIP_MEMORY_SCOPE_AGENT);
    for (int i = tid; i < B_DIM * ENC2; i += np) {        // context = max over S
        int b = i >> 10, e = i & 1023;
        float m = -3.4e38f;
        for (int s = 0; s < S_DIM; ++s)
            m = fmaxf(m, enc_outs[(s * B_DIM + b) * ENC2 + e]);
        si[b * SI_DIM + E_DIM + e] = m;
    }
    for (int i = tid; i < B_DIM * E_DIM; i += np) {       // lang embedding
        int b = i >> 9, e = i & 511;
        si[b * SI_DIM + e] = embed[(long)langs[b] * E_DIM + e];
    }
    for (int i = tid; i < B_DIM * H_DIM; i += np) {       // h0 split (parity 0)
        float h = h0[i];
        unsigned short hi = f2bf(h);
        hhi[i] = hi;
        hlo[i] = f2bf(h - bf2f(hi));
    }
}

// ---- gather token embeddings -> x hi/lo [T*B][512], row r = t*32+b ----
__global__ void k_gather_x(const float* __restrict__ embed, const int* __restrict__ tok,
                           unsigned short* __restrict__ xhi, unsigned short* __restrict__ xlo) {
    int r = blockIdx.x;
    int t = r >> 5, b = r & 31;
    long row = tok[b * T_DIM + t];
    const float4* src = (const float4*)(embed + row * E_DIM);
    ushort4* dh = (ushort4*)(xhi + (long)r * E_DIM);
    ushort4* dl = (ushort4*)(xlo + (long)r * E_DIM);
    for (int i = threadIdx.x; i < E_DIM / 4; i += blockDim.x) {
        float4 v = src[i];
        ushort4 h, l;
        h.x = f2bf(v.x); l.x = f2bf(v.x - bf2f(h.x));
        h.y = f2bf(v.y); l.y = f2bf(v.y - bf2f(h.y));
        h.z = f2bf(v.z); l.z = f2bf(v.z - bf2f(h.z));
        h.w = f2bf(v.w); l.w = f2bf(v.w - bf2f(h.w));
        dh[i] = h; dl[i] = l;
    }
}

// ---- persistent LSTM: W in registers, one grid barrier per step ----
__global__ __launch_bounds__(NTHR, 2) void k_lstm(
        const unsigned short* __restrict__ xhi, const unsigned short* __restrict__ xlo,
        unsigned short* __restrict__ hbhi, unsigned short* __restrict__ hblo,
        const float* __restrict__ si, const float* __restrict__ W_ih,
        const float* __restrict__ W_hh, const float* __restrict__ b_ih,
        const float* __restrict__ b_hh, const float* __restrict__ c0,
        float* __restrict__ out, unsigned int* __restrict__ bar) {
    __shared__ f32x4 red[8][2][2][64];     // [wave][frag][Ahalf][lane] partials (32 KB)
    __shared__ float gbuf[4][B_DIM][JT];   // gates (4 KB)
    __shared__ float sgl[4][B_DIM][JT];    // static gate bias (4 KB)

    const int tid = threadIdx.x;
    const int wv = tid >> 6, l = tid & 63, lr = l & 15, lg = l >> 4;
    const int jb = blockIdx.x * JT;

    // ---- prologue 1: static gate bias sg (fp32, block-local) ----
    {
        int c = tid >> 4, bp = tid & 15;        // c: 0..31 gate-col, bp: batch pair base
        int gate = c >> 3, jl = c & 7;
        long grow = (long)(gate * H_DIM + jb + jl);
        const float* wrow = W_ih + grow * 2048 + E_DIM;
        const float* s0 = si + bp * SI_DIM;
        const float* s1 = si + (bp + 16) * SI_DIM;
        float a0 = 0.f, a1 = 0.f;
        for (int k = 0; k < SI_DIM; k += 4) {
            float4 w  = *(const float4*)(wrow + k);
            float4 x0 = *(const float4*)(s0 + k);
            float4 x1 = *(const float4*)(s1 + k);
            a0 += w.x * x0.x + w.y * x0.y + w.z * x0.z + w.w * x0.w;
            a1 += w.x * x1.x + w.y * x1.y + w.z * x1.z + w.w * x1.w;
        }
        float bias = b_ih[grow] + b_hh[grow];
        sgl[gate][bp][jl] = a0 + bias;
        sgl[gate][bp + 16][jl] = a1 + bias;
    }

    // ---- prologue 2: load W slices into registers (hi/lo split in-reg) ----
    // frag f covers gate-cols: gate = 2f + (lr>>3), j = jb + (lr&7)
    int rowf[2];
    rowf[0] = ((lr >> 3)) * H_DIM + jb + (lr & 7);
    rowf[1] = (2 + (lr >> 3)) * H_DIM + jb + (lr & 7);

    FragAB WHh[2][ITH], WHl[2][ITH], WXh[2][ITX], WXl[2][ITX];
    #pragma unroll
    for (int f = 0; f < 2; ++f) {
        #pragma unroll
        for (int it = 0; it < ITH; ++it)
            packW(W_hh + (long)rowf[f] * H_DIM + (wv * KHW + it * 32 + 4 * lg),
                  WHh[f][it], WHl[f][it]);
        #pragma unroll
        for (int it = 0; it < ITX; ++it)
            packW(W_ih + (long)rowf[f] * 2048 + (wv * KXW + it * 32 + 4 * lg),
                  WXh[f][it], WXl[f][it]);
    }

    // ---- prologue 3: cell state in register (thread<256 owns cell (b, jb+jl)) ----
    const int ab = tid >> 3, ajl = tid & 7;     // activation mapping
    float creg = 0.f;
    if (tid < 256) creg = c0[ab * H_DIM + jb + ajl];

    __syncthreads();   // sgl ready

    // ---- time loop ----
    #pragma unroll 1
    for (int t = 0; t < T_DIM; ++t) {
        const unsigned short* hh = hbhi + (size_t)(t & 1) * HB;
        const unsigned short* hl = hblo + (size_t)(t & 1) * HB;
        unsigned short* hh_n = hbhi + (size_t)((t & 1) ^ 1) * HB;
        unsigned short* hl_n = hblo + (size_t)((t & 1) ^ 1) * HB;

        f32x4 acc00 = {}, acc01 = {}, acc10 = {}, acc11 = {};  // [frag][Ahalf]

        // recurrent term: this wave's K-slice of W_hh
        {
            const unsigned short* ah = hh + lr * H_DIM + 4 * lg;
            const unsigned short* al = hl + lr * H_DIM + 4 * lg;
            const int kb = wv * KHW;
            #pragma unroll
            for (int it = 0; it < ITH; ++it) {
                const int k0 = kb + it * 32;
                FragAB Ah0, Ah1, Al0, Al1;
                LOADFRAG(Ah0, ah + k0); LOADFRAG(Ah1, ah + 16 * H_DIM + k0);
                LOADFRAG(Al0, al + k0); LOADFRAG(Al1, al + 16 * H_DIM + k0);
                acc00 = mfma16(Ah0.v, WHh[0][it].v, acc00);
                acc00 = mfma16(Ah0.v, WHl[0][it].v, acc00);
                acc00 = mfma16(Al0.v, WHh[0][it].v, acc00);
                acc01 = mfma16(Ah1.v, WHh[0][it].v, acc01);
                acc01 = mfma16(Ah1.v, WHl[0][it].v, acc01);
                acc01 = mfma16(Al1.v, WHh[0][it].v, acc01);
                acc10 = mfma16(Ah0.v, WHh[1][it].v, acc10);
                acc10 = mfma16(Ah0.v, WHl[1][it].v, acc10);
                acc10 = mfma16(Al0.v, WHh[1][it].v, acc10);
                acc11 = mfma16(Ah1.v, WHh[1][it].v, acc11);
                acc11 = mfma16(Ah1.v, WHl[1][it].v, acc11);
                acc11 = mfma16(Al1.v, WHh[1][it].v, acc11);
            }
        }
        // input term: this wave's K-slice of W_ih[:, :512], A = x_t
        {
            const unsigned short* ax = xhi + (size_t)(t * B_DIM + lr) * E_DIM + 4 * lg;
            const unsigned short* axl = xlo + (size_t)(t * B_DIM + lr) * E_DIM + 4 * lg;
            const int kb = wv * KXW;
            #pragma unroll
            for (int it = 0; it < ITX; ++it) {
                const int k0 = kb + it * 32;
                FragAB Ah0, Ah1, Al0, Al1;
                LOADFRAG(Ah0, ax + k0);  LOADFRAG(Ah1, ax + 16 * E_DIM + k0);
                LOADFRAG(Al0, axl + k0); LOADFRAG(Al1, axl + 16 * E_DIM + k0);
                acc00 = mfma16(Ah0.v, WXh[0][it].v, acc00);
                acc00 = mfma16(Ah0.v, WXl[0][it].v, acc00);
                acc00 = mfma16(Al0.v, WXh[0][it].v, acc00);
                acc01 = mfma16(Ah1.v, WXh[0][it].v, acc01);
                acc01 = mfma16(Ah1.v, WXl[0][it].v, acc01);
                acc01 = mfma16(Al1.v, WXh[0][it].v, acc01);
                acc10 = mfma16(Ah0.v, WXh[1][it].v, acc10);
                acc10 = mfma16(Ah0.v, WXl[1][it].v, acc10);
                acc10 = mfma16(Al0.v, WXh[1][it].v, acc10);
                acc11 = mfma16(Ah1.v, WXh[1][it].v, acc11);
                acc11 = mfma16(Ah1.v, WXl[1][it].v, acc11);
                acc11 = mfma16(Al1.v, WXh[1][it].v, acc11);
            }
        }

        // cross-wave K reduction
        red[wv][0][0][l] = acc00; red[wv][0][1][l] = acc01;
        red[wv][1][0][l] = acc10; red[wv][1][1][l] = acc11;
        __syncthreads();
        #pragma unroll
        for (int o = tid; o < 1024; o += NTHR) {
            int f = o >> 9, m = (o >> 8) & 1, l2 = (o >> 2) & 63, r = o & 3;
            float s = 0.f;
            #pragma unroll
            for (int w = 0; w < 8; ++w) s += red[w][f][m][l2][r];
            int b = 16 * m + 4 * (l2 >> 4) + r;
            int c = l2 & 15;
            int gate = 2 * f + (c >> 3), jl = c & 7;
            gbuf[gate][b][jl] = s + sgl[gate][b][jl];
        }
        __syncthreads();

        // activation: thread<256 owns cell (ab, jb+ajl); c stays in register
        if (tid < 256) {
            float iv = gbuf[0][ab][ajl], fv = gbuf[1][ab][ajl];
            float gv = gbuf[2][ab][ajl], ov = gbuf[3][ab][ajl];
            float cn = sigf(fv) * creg + sigf(iv) * tanhf(gv);
            float hn = sigf(ov) * tanhf(cn);
            creg = cn;
            int j = jb + ajl;
            unsigned short hi = f2bf(hn);
            hh_n[ab * H_DIM + j] = hi;
            hl_n[ab * H_DIM + j] = f2bf(hn - bf2f(hi));
            out[(size_t)t * HB + ab * H_DIM + j] = hn;
        }

        // device-wide barrier (monotonic counter; all 256 blocks co-resident)
        __threadfence();
        __syncthreads();
        if (tid == 0) {
            __hip_atomic_fetch_add(bar, 1u, __ATOMIC_ACQ_REL, __HIP_MEMORY_SCOPE_AGENT);
            const unsigned tgt = (unsigned)NBLK * (unsigned)(t + 1);
            while (__hip_atomic_load(bar, __ATOMIC_ACQUIRE, __HIP_MEMORY_SCOPE_AGENT) < tgt)
                __builtin_amdgcn_s_sleep(2);
        }
        __syncthreads();
    }
}

extern "C" void kernel_launch(void* const* d_in, const int* in_sizes, int n_in,
                              void* d_out, int out_size, void* d_ws, size_t ws_size,
                              hipStream_t stream) {
    const float* embed    = (const float*)d_in[0];
    const float* enc_outs = (const float*)d_in[1];
    const float* h0       = (const float*)d_in[2];
    const float* c0       = (const float*)d_in[3];
    const float* W_ih     = (const float*)d_in[4];
    const float* W_hh     = (const float*)d_in[5];
    const float* b_ih     = (const float*)d_in[6];
    const float* b_hh     = (const float*)d_in[7];
    const int*   tok      = (const int*)d_in[8];
    const int*   langs    = (const int*)d_in[9];
    float* out = (float*)d_out;

    char* ws = (char*)d_ws;
    unsigned short* x_hi = (unsigned short*)(ws + 0);
    unsigned short* x_lo = (unsigned short*)(ws + 4194304);
    unsigned short* hbhi = (unsigned short*)(ws + 8388608);
    unsigned short* hblo = (unsigned short*)(ws + 8650752);
    float* si            = (float*)(ws + 8912896);
    unsigned int* bar    = (unsigned int*)(ws + 9109504);

    hipLaunchKernelGGL(k_prep, dim3(512), dim3(256), 0, stream,
                       enc_outs, embed, langs, h0, si, hbhi, hblo, bar);
    hipLaunchKernelGGL(k_gather_x, dim3(T_DIM * B_DIM), dim3(128), 0, stream,
                       embed, tok, x_hi, x_lo);
    hipLaunchKernelGGL(k_lstm, dim3(NBLK), dim3(NTHR), 0, stream,
                       x_hi, x_lo, hbhi, hblo, si, W_ih, W_hh, b_ih, b_hh, c0,
                       out, bar);
}

// Round 4
// 8489.676 us; speedup vs baseline: 1.6376x; 1.1135x over previous
//
#include <hip/hip_runtime.h>
#include <math.h>

// ---------------- problem dims ----------------
#define E_DIM 512     // embedding dim
#define H_DIM 2048    // hidden
#define G_DIM 8192    // 4*H
#define B_DIM 32      // batch
#define T_DIM 128     // target time
#define S_DIM 128     // source time
#define ENC2  1024    // 2*encoder_hidden
#define SI_DIM 1536   // E + 2*enc (static input)

#define NBLK 256      // persistent blocks (1 per CU)
#define NTHR 512      // 8 waves
#define JT   8        // hidden cols per block
#define KHW  (H_DIM/8)   // 256: W_hh K-slice per wave
#define KXW  (E_DIM/8)   // 64:  W_ih K-slice per wave
#define ITH  (KHW/32)    // 8 k0-iters (whh)
#define ITX  (KXW/32)    // 2 k0-iters (wih)
#define HB   (B_DIM*H_DIM)   // 65536 elements per h buffer

// ---------------- workspace layout (bytes) ----------------
// x_hi  bf16 [4096][512]  @ 0        (4194304)
// x_lo  bf16 [4096][512]  @ 4194304  (4194304)
// hb_hi bf16 2x[32][2048] @ 8388608  (262144)
// hb_lo bf16 2x[32][2048] @ 8650752  (262144)
// si    f32  [32][1536]   @ 8912896  (196608)
// flags u32  [256]x16     @ 9109504  (16384)   64B-strided arrival flags
// total ~9.1 MB

typedef __bf16 bf16_t;
typedef bf16_t bf16x8 __attribute__((ext_vector_type(8)));
typedef float f32x4 __attribute__((ext_vector_type(4)));

union FragAB { bf16x8 v; uint2 u2[2]; unsigned short s[8]; };

#define LOADFRAG(dst, base) do { const uint2* _p = (const uint2*)(base); \
    (dst).u2[0] = _p[0]; (dst).u2[1] = _p[4]; } while (0)

__device__ __forceinline__ unsigned short f2bf(float x) {
    unsigned u = __float_as_uint(x);
    u += 0x7FFFu + ((u >> 16) & 1u);   // RNE
    return (unsigned short)(u >> 16);
}
__device__ __forceinline__ float bf2f(unsigned short s) {
    return __uint_as_float(((unsigned)s) << 16);
}
__device__ __forceinline__ f32x4 mfma16(bf16x8 a, bf16x8 b, f32x4 c) {
    return __builtin_amdgcn_mfma_f32_16x16x32_bf16(a, b, c, 0, 0, 0);
}
__device__ __forceinline__ float sigf(float x) { return 1.f / (1.f + expf(-x)); }

// pack 8 consecutive-k fp32 W elements (two float4: +0 and +16 elems) into hi/lo bf16 frags
__device__ __forceinline__ void packW(const float* src, FragAB& hi, FragAB& lo) {
    float4 w0 = *(const float4*)src;
    float4 w1 = *(const float4*)(src + 16);
    float v[8] = {w0.x, w0.y, w0.z, w0.w, w1.x, w1.y, w1.z, w1.w};
    #pragma unroll
    for (int j = 0; j < 8; ++j) {
        unsigned short h = f2bf(v[j]);
        hi.s[j] = h;
        lo.s[j] = f2bf(v[j] - bf2f(h));
    }
}

// ---- prep: context max-pool, lang embed, h0 split, flag reset ----
__global__ void k_prep(const float* __restrict__ enc_outs, const float* __restrict__ embed,
                       const int* __restrict__ langs, const float* __restrict__ h0,
                       float* __restrict__ si, unsigned short* __restrict__ hhi,
                       unsigned short* __restrict__ hlo, unsigned int* __restrict__ flags) {
    int tid = blockIdx.x * blockDim.x + threadIdx.x;
    int np = gridDim.x * blockDim.x;
    for (int i = tid; i < NBLK * 16; i += np)
        flags[i] = 0u;
    for (int i = tid; i < B_DIM * ENC2; i += np) {        // context = max over S
        int b = i >> 10, e = i & 1023;
        float m = -3.4e38f;
        for (int s = 0; s < S_DIM; ++s)
            m = fmaxf(m, enc_outs[(s * B_DIM + b) * ENC2 + e]);
        si[b * SI_DIM + E_DIM + e] = m;
    }
    for (int i = tid; i < B_DIM * E_DIM; i += np) {       // lang embedding
        int b = i >> 9, e = i & 511;
        si[b * SI_DIM + e] = embed[(long)langs[b] * E_DIM + e];
    }
    for (int i = tid; i < B_DIM * H_DIM; i += np) {       // h0 split (parity 0)
        float h = h0[i];
        unsigned short hi = f2bf(h);
        hhi[i] = hi;
        hlo[i] = f2bf(h - bf2f(hi));
    }
}

// ---- gather token embeddings -> x hi/lo [T*B][512], row r = t*32+b ----
__global__ void k_gather_x(const float* __restrict__ embed, const int* __restrict__ tok,
                           unsigned short* __restrict__ xhi, unsigned short* __restrict__ xlo) {
    int r = blockIdx.x;
    int t = r >> 5, b = r & 31;
    long row = tok[b * T_DIM + t];
    const float4* src = (const float4*)(embed + row * E_DIM);
    ushort4* dh = (ushort4*)(xhi + (long)r * E_DIM);
    ushort4* dl = (ushort4*)(xlo + (long)r * E_DIM);
    for (int i = threadIdx.x; i < E_DIM / 4; i += blockDim.x) {
        float4 v = src[i];
        ushort4 h, l;
        h.x = f2bf(v.x); l.x = f2bf(v.x - bf2f(h.x));
        h.y = f2bf(v.y); l.y = f2bf(v.y - bf2f(h.y));
        h.z = f2bf(v.z); l.z = f2bf(v.z - bf2f(h.z));
        h.w = f2bf(v.w); l.w = f2bf(v.w - bf2f(h.w));
        dh[i] = h; dl[i] = l;
    }
}

// ---- persistent LSTM: W in registers, leaderless flag barrier per step ----
__global__ __launch_bounds__(NTHR, 2) void k_lstm(
        const unsigned short* __restrict__ xhi, const unsigned short* __restrict__ xlo,
        unsigned short* __restrict__ hbhi, unsigned short* __restrict__ hblo,
        const float* __restrict__ si, const float* __restrict__ W_ih,
        const float* __restrict__ W_hh, const float* __restrict__ b_ih,
        const float* __restrict__ b_hh, const float* __restrict__ c0,
        float* __restrict__ out, unsigned int* __restrict__ flags) {
    __shared__ f32x4 red[8][2][2][64];     // [wave][frag][Ahalf][lane] partials (32 KB)
    __shared__ float gbuf[4][B_DIM][JT];   // gates (4 KB)
    __shared__ float sgl[4][B_DIM][JT];    // static gate bias (4 KB)

    const int tid = threadIdx.x;
    const int wv = tid >> 6, l = tid & 63, lr = l & 15, lg = l >> 4;
    const int jb = blockIdx.x * JT;

    // ---- prologue 1: static gate bias sg (fp32, block-local) ----
    {
        int c = tid >> 4, bp = tid & 15;        // c: 0..31 gate-col, bp: batch pair base
        int gate = c >> 3, jl = c & 7;
        long grow = (long)(gate * H_DIM + jb + jl);
        const float* wrow = W_ih + grow * 2048 + E_DIM;
        const float* s0 = si + bp * SI_DIM;
        const float* s1 = si + (bp + 16) * SI_DIM;
        float a0 = 0.f, a1 = 0.f;
        for (int k = 0; k < SI_DIM; k += 4) {
            float4 w  = *(const float4*)(wrow + k);
            float4 x0 = *(const float4*)(s0 + k);
            float4 x1 = *(const float4*)(s1 + k);
            a0 += w.x * x0.x + w.y * x0.y + w.z * x0.z + w.w * x0.w;
            a1 += w.x * x1.x + w.y * x1.y + w.z * x1.z + w.w * x1.w;
        }
        float bias = b_ih[grow] + b_hh[grow];
        sgl[gate][bp][jl] = a0 + bias;
        sgl[gate][bp + 16][jl] = a1 + bias;
    }

    // ---- prologue 2: load W slices into registers (hi/lo split in-reg) ----
    // frag f covers gate-cols: gate = 2f + (lr>>3), j = jb + (lr&7)
    int rowf[2];
    rowf[0] = ((lr >> 3)) * H_DIM + jb + (lr & 7);
    rowf[1] = (2 + (lr >> 3)) * H_DIM + jb + (lr & 7);

    FragAB WHh[2][ITH], WHl[2][ITH], WXh[2][ITX], WXl[2][ITX];
    #pragma unroll
    for (int f = 0; f < 2; ++f) {
        #pragma unroll
        for (int it = 0; it < ITH; ++it)
            packW(W_hh + (long)rowf[f] * H_DIM + (wv * KHW + it * 32 + 4 * lg),
                  WHh[f][it], WHl[f][it]);
        #pragma unroll
        for (int it = 0; it < ITX; ++it)
            packW(W_ih + (long)rowf[f] * 2048 + (wv * KXW + it * 32 + 4 * lg),
                  WXh[f][it], WXl[f][it]);
    }

    // ---- prologue 3: cell state in register (thread<256 owns cell (b, jb+jl)) ----
    const int ab = tid >> 3, ajl = tid & 7;     // activation mapping
    float creg = 0.f;
    if (tid < 256) creg = c0[ab * H_DIM + jb + ajl];

    __syncthreads();   // sgl ready

    // ---- time loop ----
    #pragma unroll 1
    for (int t = 0; t < T_DIM; ++t) {
        f32x4 acc00 = {}, acc01 = {}, acc10 = {}, acc11 = {};  // [frag][Ahalf]

        // input term FIRST (independent of h_t; overlaps barrier propagation)
        {
            const unsigned short* ax  = xhi + (size_t)(t * B_DIM + lr) * E_DIM + 4 * lg;
            const unsigned short* axl = xlo + (size_t)(t * B_DIM + lr) * E_DIM + 4 * lg;
            const int kb = wv * KXW;
            #pragma unroll
            for (int it = 0; it < ITX; ++it) {
                const int k0 = kb + it * 32;
                FragAB Ah0, Ah1, Al0, Al1;
                LOADFRAG(Ah0, ax + k0);  LOADFRAG(Ah1, ax + 16 * E_DIM + k0);
                LOADFRAG(Al0, axl + k0); LOADFRAG(Al1, axl + 16 * E_DIM + k0);
                acc00 = mfma16(Ah0.v, WXh[0][it].v, acc00);
                acc00 = mfma16(Ah0.v, WXl[0][it].v, acc00);
                acc00 = mfma16(Al0.v, WXh[0][it].v, acc00);
                acc01 = mfma16(Ah1.v, WXh[0][it].v, acc01);
                acc01 = mfma16(Ah1.v, WXl[0][it].v, acc01);
                acc01 = mfma16(Al1.v, WXh[0][it].v, acc01);
                acc10 = mfma16(Ah0.v, WXh[1][it].v, acc10);
                acc10 = mfma16(Ah0.v, WXl[1][it].v, acc10);
                acc10 = mfma16(Al0.v, WXh[1][it].v, acc10);
                acc11 = mfma16(Ah1.v, WXh[1][it].v, acc11);
                acc11 = mfma16(Ah1.v, WXl[1][it].v, acc11);
                acc11 = mfma16(Al1.v, WXh[1][it].v, acc11);
            }
        }

        // wait until all blocks published h_t (t>0). Wave 0 polls all 256 flags.
        if (t > 0) {
            if (tid < 64) {
                const unsigned tgt = (unsigned)t;
                for (;;) {
                    bool ok = true;
                    #pragma unroll
                    for (int i = 0; i < 4; ++i) {
                        unsigned v = __hip_atomic_load(
                            flags + (size_t)(tid + 64 * i) * 16,
                            __ATOMIC_RELAXED, __HIP_MEMORY_SCOPE_AGENT);
                        ok = ok && (v >= tgt);
                    }
                    if (__all(ok)) break;
                    __builtin_amdgcn_s_sleep(2);
                }
                // one acquire load -> invalidate stale L1/L2 before h reads
                unsigned d = __hip_atomic_load(flags, __ATOMIC_ACQUIRE,
                                               __HIP_MEMORY_SCOPE_AGENT);
                asm volatile("" :: "v"(d));
            }
            __syncthreads();
        }

        const unsigned short* hh = hbhi + (size_t)(t & 1) * HB;
        const unsigned short* hl = hblo + (size_t)(t & 1) * HB;
        unsigned short* hh_n = hbhi + (size_t)((t & 1) ^ 1) * HB;
        unsigned short* hl_n = hblo + (size_t)((t & 1) ^ 1) * HB;

        // recurrent term: this wave's K-slice of W_hh
        {
            const unsigned short* ah = hh + lr * H_DIM + 4 * lg;
            const unsigned short* al = hl + lr * H_DIM + 4 * lg;
            const int kb = wv * KHW;
            #pragma unroll
            for (int it = 0; it < ITH; ++it) {
                const int k0 = kb + it * 32;
                FragAB Ah0, Ah1, Al0, Al1;
                LOADFRAG(Ah0, ah + k0); LOADFRAG(Ah1, ah + 16 * H_DIM + k0);
                LOADFRAG(Al0, al + k0); LOADFRAG(Al1, al + 16 * H_DIM + k0);
                acc00 = mfma16(Ah0.v, WHh[0][it].v, acc00);
                acc00 = mfma16(Ah0.v, WHl[0][it].v, acc00);
                acc00 = mfma16(Al0.v, WHh[0][it].v, acc00);
                acc01 = mfma16(Ah1.v, WHh[0][it].v, acc01);
                acc01 = mfma16(Ah1.v, WHl[0][it].v, acc01);
                acc01 = mfma16(Al1.v, WHh[0][it].v, acc01);
                acc10 = mfma16(Ah0.v, WHh[1][it].v, acc10);
                acc10 = mfma16(Ah0.v, WHl[1][it].v, acc10);
                acc10 = mfma16(Al0.v, WHh[1][it].v, acc10);
                acc11 = mfma16(Ah1.v, WHh[1][it].v, acc11);
                acc11 = mfma16(Ah1.v, WHl[1][it].v, acc11);
                acc11 = mfma16(Al1.v, WHh[1][it].v, acc11);
            }
        }

        // cross-wave K reduction
        red[wv][0][0][l] = acc00; red[wv][0][1][l] = acc01;
        red[wv][1][0][l] = acc10; red[wv][1][1][l] = acc11;
        __syncthreads();
        #pragma unroll
        for (int o = tid; o < 1024; o += NTHR) {
            int f = o >> 9, m = (o >> 8) & 1, l2 = (o >> 2) & 63, r = o & 3;
            float s = 0.f;
            #pragma unroll
            for (int w = 0; w < 8; ++w) s += red[w][f][m][l2][r];
            int b = 16 * m + 4 * (l2 >> 4) + r;
            int c = l2 & 15;
            int gate = 2 * f + (c >> 3), jl = c & 7;
            gbuf[gate][b][jl] = s + sgl[gate][b][jl];
        }
        __syncthreads();

        // activation: thread<256 owns cell (ab, jb+ajl); c stays in register
        if (tid < 256) {
            float iv = gbuf[0][ab][ajl], fv = gbuf[1][ab][ajl];
            float gv = gbuf[2][ab][ajl], ov = gbuf[3][ab][ajl];
            float cn = sigf(fv) * creg + sigf(iv) * tanhf(gv);
            float hn = sigf(ov) * tanhf(cn);
            creg = cn;
            int j = jb + ajl;
            unsigned short hi = f2bf(hn);
            hh_n[ab * H_DIM + j] = hi;
            hl_n[ab * H_DIM + j] = f2bf(hn - bf2f(hi));
            out[(size_t)t * HB + ab * H_DIM + j] = hn;
        }

        // arrive: publish h_{t+1} with one release-store to our own flag
        if (t < T_DIM - 1) {
            __threadfence();
            __syncthreads();
            if (tid == 0)
                __hip_atomic_store(flags + (size_t)blockIdx.x * 16,
                                   (unsigned)(t + 1), __ATOMIC_RELEASE,
                                   __HIP_MEMORY_SCOPE_AGENT);
        }
    }
}

extern "C" void kernel_launch(void* const* d_in, const int* in_sizes, int n_in,
                              void* d_out, int out_size, void* d_ws, size_t ws_size,
                              hipStream_t stream) {
    const float* embed    = (const float*)d_in[0];
    const float* enc_outs = (const float*)d_in[1];
    const float* h0       = (const float*)d_in[2];
    const float* c0       = (const float*)d_in[3];
    const float* W_ih     = (const float*)d_in[4];
    const float* W_hh     = (const float*)d_in[5];
    const float* b_ih     = (const float*)d_in[6];
    const float* b_hh     = (const float*)d_in[7];
    const int*   tok      = (const int*)d_in[8];
    const int*   langs    = (const int*)d_in[9];
    float* out = (float*)d_out;

    char* ws = (char*)d_ws;
    unsigned short* x_hi = (unsigned short*)(ws + 0);
    unsigned short* x_lo = (unsigned short*)(ws + 4194304);
    unsigned short* hbhi = (unsigned short*)(ws + 8388608);
    unsigned short* hblo = (unsigned short*)(ws + 8650752);
    float* si            = (float*)(ws + 8912896);
    unsigned int* flags  = (unsigned int*)(ws + 9109504);

    hipLaunchKernelGGL(k_prep, dim3(512), dim3(256), 0, stream,
                       enc_outs, embed, langs, h0, si, hbhi, hblo, flags);
    hipLaunchKernelGGL(k_gather_x, dim3(T_DIM * B_DIM), dim3(128), 0, stream,
                       embed, tok, x_hi, x_lo);
    hipLaunchKernelGGL(k_lstm, dim3(NBLK), dim3(NTHR), 0, stream,
                       x_hi, x_lo, hbhi, hblo, si, W_ih, W_hh, b_ih, b_hh, c0,
                       out, flags);
}

// Round 5
// 8484.156 us; speedup vs baseline: 1.6386x; 1.0007x over previous
//
#include <hip/hip_runtime.h>
#include <math.h>

// ---------------- problem dims ----------------
#define E_DIM 512     // embedding dim
#define H_DIM 2048    // hidden
#define G_DIM 8192    // 4*H
#define B_DIM 32      // batch
#define T_DIM 128     // target time
#define S_DIM 128     // source time
#define ENC2  1024    // 2*encoder_hidden
#define SI_DIM 1536   // E + 2*enc (static input)

#define NBLK 256      // persistent blocks (1 per CU)
#define NTHR 512      // 8 waves
#define JT   8        // hidden cols per block
#define KHW  (H_DIM/8)   // 256: W_hh K-slice per wave
#define KXW  (E_DIM/8)   // 64:  W_ih K-slice per wave
#define ITH  (KHW/32)    // 8 k0-iters (whh)
#define ITX  (KXW/32)    // 2 k0-iters (wih)
#define HB   (B_DIM*H_DIM)   // 65536 elements per h buffer

// ---------------- workspace layout (bytes) ----------------
// x_hi  bf16 [4096][512]  @ 0        (4194304)
// x_lo  bf16 [4096][512]  @ 4194304  (4194304)
// hb_hi bf16 2x[32][2048] @ 8388608  (262144)
// hb_lo bf16 2x[32][2048] @ 8650752  (262144)
// si    f32  [32][1536]   @ 8912896  (196608)
// flags u32  [256]x16     @ 9109504  (16384)   64B-strided arrival flags
// total ~9.1 MB

typedef __bf16 bf16_t;
typedef bf16_t bf16x8 __attribute__((ext_vector_type(8)));
typedef float f32x4 __attribute__((ext_vector_type(4)));

__device__ __forceinline__ unsigned short f2bf(float x) {
    unsigned u = __float_as_uint(x);
    u += 0x7FFFu + ((u >> 16) & 1u);   // RNE
    return (unsigned short)(u >> 16);
}
__device__ __forceinline__ float bf2f(unsigned short s) {
    return __uint_as_float(((unsigned)s) << 16);
}
__device__ __forceinline__ unsigned pack2(float a, float b) {
    return (unsigned)f2bf(a) | ((unsigned)f2bf(b) << 16);
}
// register-only fragment construction (NO unions -> no scratch demotion)
__device__ __forceinline__ bf16x8 frag_from(uint2 lo, uint2 hi) {
    uint4 q; q.x = lo.x; q.y = lo.y; q.z = hi.x; q.w = hi.y;
    return __builtin_bit_cast(bf16x8, q);
}
// fragment layout: elems 0..3 at base+0..3, elems 4..7 at base+16..19 (shorts)
__device__ __forceinline__ bf16x8 load_frag(const unsigned short* base) {
    const uint2* p = (const uint2*)base;
    uint2 a = p[0], b = p[4];
    return frag_from(a, b);
}
__device__ __forceinline__ f32x4 mfma16(bf16x8 a, bf16x8 b, f32x4 c) {
    return __builtin_amdgcn_mfma_f32_16x16x32_bf16(a, b, c, 0, 0, 0);
}
__device__ __forceinline__ float sigf(float x) { return 1.f / (1.f + expf(-x)); }

// pack 8 consecutive-k fp32 W elements (two float4: +0 and +16) into hi/lo bf16 frags
__device__ __forceinline__ void packW(const float* src, bf16x8& hi, bf16x8& lo) {
    float4 w0 = *(const float4*)src;
    float4 w1 = *(const float4*)(src + 16);
    uint4 qh;
    qh.x = pack2(w0.x, w0.y); qh.y = pack2(w0.z, w0.w);
    qh.z = pack2(w1.x, w1.y); qh.w = pack2(w1.z, w1.w);
    float r0 = w0.x - bf2f((unsigned short)(qh.x & 0xFFFF));
    float r1 = w0.y - bf2f((unsigned short)(qh.x >> 16));
    float r2 = w0.z - bf2f((unsigned short)(qh.y & 0xFFFF));
    float r3 = w0.w - bf2f((unsigned short)(qh.y >> 16));
    float r4 = w1.x - bf2f((unsigned short)(qh.z & 0xFFFF));
    float r5 = w1.y - bf2f((unsigned short)(qh.z >> 16));
    float r6 = w1.z - bf2f((unsigned short)(qh.w & 0xFFFF));
    float r7 = w1.w - bf2f((unsigned short)(qh.w >> 16));
    uint4 ql;
    ql.x = pack2(r0, r1); ql.y = pack2(r2, r3);
    ql.z = pack2(r4, r5); ql.w = pack2(r6, r7);
    hi = __builtin_bit_cast(bf16x8, qh);
    lo = __builtin_bit_cast(bf16x8, ql);
}

// ---- prep: context max-pool, lang embed, h0 split, flag reset ----
__global__ void k_prep(const float* __restrict__ enc_outs, const float* __restrict__ embed,
                       const int* __restrict__ langs, const float* __restrict__ h0,
                       float* __restrict__ si, unsigned short* __restrict__ hhi,
                       unsigned short* __restrict__ hlo, unsigned int* __restrict__ flags) {
    int tid = blockIdx.x * blockDim.x + threadIdx.x;
    int np = gridDim.x * blockDim.x;
    for (int i = tid; i < NBLK * 16; i += np)
        flags[i] = 0u;
    for (int i = tid; i < B_DIM * ENC2; i += np) {        // context = max over S
        int b = i >> 10, e = i & 1023;
        float m = -3.4e38f;
        for (int s = 0; s < S_DIM; ++s)
            m = fmaxf(m, enc_outs[(s * B_DIM + b) * ENC2 + e]);
        si[b * SI_DIM + E_DIM + e] = m;
    }
    for (int i = tid; i < B_DIM * E_DIM; i += np) {       // lang embedding
        int b = i >> 9, e = i & 511;
        si[b * SI_DIM + e] = embed[(long)langs[b] * E_DIM + e];
    }
    for (int i = tid; i < B_DIM * H_DIM; i += np) {       // h0 split (parity 0)
        float h = h0[i];
        unsigned short hi = f2bf(h);
        hhi[i] = hi;
        hlo[i] = f2bf(h - bf2f(hi));
    }
}

// ---- gather token embeddings -> x hi/lo [T*B][512], row r = t*32+b ----
__global__ void k_gather_x(const float* __restrict__ embed, const int* __restrict__ tok,
                           unsigned short* __restrict__ xhi, unsigned short* __restrict__ xlo) {
    int r = blockIdx.x;
    int t = r >> 5, b = r & 31;
    long row = tok[b * T_DIM + t];
    const float4* src = (const float4*)(embed + row * E_DIM);
    ushort4* dh = (ushort4*)(xhi + (long)r * E_DIM);
    ushort4* dl = (ushort4*)(xlo + (long)r * E_DIM);
    for (int i = threadIdx.x; i < E_DIM / 4; i += blockDim.x) {
        float4 v = src[i];
        ushort4 h, l;
        h.x = f2bf(v.x); l.x = f2bf(v.x - bf2f(h.x));
        h.y = f2bf(v.y); l.y = f2bf(v.y - bf2f(h.y));
        h.z = f2bf(v.z); l.z = f2bf(v.z - bf2f(h.z));
        h.w = f2bf(v.w); l.w = f2bf(v.w - bf2f(h.w));
        dh[i] = h; dl[i] = l;
    }
}

// ---- persistent LSTM: W in registers, leaderless flag barrier per step ----
__global__ __launch_bounds__(NTHR, 1) void k_lstm(
        const unsigned short* __restrict__ xhi, const unsigned short* __restrict__ xlo,
        unsigned short* __restrict__ hbhi, unsigned short* __restrict__ hblo,
        const float* __restrict__ si, const float* __restrict__ W_ih,
        const float* __restrict__ W_hh, const float* __restrict__ b_ih,
        const float* __restrict__ b_hh, const float* __restrict__ c0,
        float* __restrict__ out, unsigned int* __restrict__ flags) {
    __shared__ f32x4 red[8][2][2][64];     // [wave][frag][Ahalf][lane] partials (32 KB)
    __shared__ float gbuf[4][B_DIM][JT];   // gates (4 KB)
    __shared__ float sgl[4][B_DIM][JT];    // static gate bias (4 KB)

    const int tid = threadIdx.x;
    const int wv = tid >> 6, l = tid & 63, lr = l & 15, lg = l >> 4;
    const int jb = blockIdx.x * JT;

    // ---- prologue 1: static gate bias sg (fp32, block-local) ----
    {
        int c = tid >> 4, bp = tid & 15;        // c: 0..31 gate-col, bp: batch pair base
        int gate = c >> 3, jl = c & 7;
        long grow = (long)(gate * H_DIM + jb + jl);
        const float* wrow = W_ih + grow * 2048 + E_DIM;
        const float* s0 = si + bp * SI_DIM;
        const float* s1 = si + (bp + 16) * SI_DIM;
        float a0 = 0.f, a1 = 0.f;
        for (int k = 0; k < SI_DIM; k += 4) {
            float4 w  = *(const float4*)(wrow + k);
            float4 x0 = *(const float4*)(s0 + k);
            float4 x1 = *(const float4*)(s1 + k);
            a0 += w.x * x0.x + w.y * x0.y + w.z * x0.z + w.w * x0.w;
            a1 += w.x * x1.x + w.y * x1.y + w.z * x1.z + w.w * x1.w;
        }
        float bias = b_ih[grow] + b_hh[grow];
        sgl[gate][bp][jl] = a0 + bias;
        sgl[gate][bp + 16][jl] = a1 + bias;
    }

    // ---- prologue 2: load W slices into registers (hi/lo split in-reg) ----
    // frag f covers gate-cols: gate = 2f + (lr>>3), j = jb + (lr&7)
    int rowf[2];
    rowf[0] = ((lr >> 3)) * H_DIM + jb + (lr & 7);
    rowf[1] = (2 + (lr >> 3)) * H_DIM + jb + (lr & 7);

    bf16x8 WHh[2][ITH], WHl[2][ITH], WXh[2][ITX], WXl[2][ITX];
    #pragma unroll
    for (int f = 0; f < 2; ++f) {
        #pragma unroll
        for (int it = 0; it < ITH; ++it)
            packW(W_hh + (long)rowf[f] * H_DIM + (wv * KHW + it * 32 + 4 * lg),
                  WHh[f][it], WHl[f][it]);
        #pragma unroll
        for (int it = 0; it < ITX; ++it)
            packW(W_ih + (long)rowf[f] * 2048 + (wv * KXW + it * 32 + 4 * lg),
                  WXh[f][it], WXl[f][it]);
    }

    // ---- prologue 3: cell state in register (thread<256 owns cell (b, jb+jl)) ----
    const int ab = tid >> 3, ajl = tid & 7;     // activation mapping
    float creg = 0.f;
    if (tid < 256) creg = c0[ab * H_DIM + jb + ajl];

    __syncthreads();   // sgl ready

    // ---- time loop ----
    #pragma unroll 1
    for (int t = 0; t < T_DIM; ++t) {
        f32x4 acc00 = {}, acc01 = {}, acc10 = {}, acc11 = {};  // [frag][Ahalf]

        // input term FIRST (independent of h_t; overlaps barrier propagation)
        {
            const unsigned short* ax  = xhi + (size_t)(t * B_DIM + lr) * E_DIM + 4 * lg;
            const unsigned short* axl = xlo + (size_t)(t * B_DIM + lr) * E_DIM + 4 * lg;
            const int kb = wv * KXW;
            #pragma unroll
            for (int it = 0; it < ITX; ++it) {
                const int k0 = kb + it * 32;
                bf16x8 Ah0 = load_frag(ax + k0);
                bf16x8 Ah1 = load_frag(ax + 16 * E_DIM + k0);
                bf16x8 Al0 = load_frag(axl + k0);
                bf16x8 Al1 = load_frag(axl + 16 * E_DIM + k0);
                acc00 = mfma16(Ah0, WXh[0][it], acc00);
                acc00 = mfma16(Ah0, WXl[0][it], acc00);
                acc00 = mfma16(Al0, WXh[0][it], acc00);
                acc01 = mfma16(Ah1, WXh[0][it], acc01);
                acc01 = mfma16(Ah1, WXl[0][it], acc01);
                acc01 = mfma16(Al1, WXh[0][it], acc01);
                acc10 = mfma16(Ah0, WXh[1][it], acc10);
                acc10 = mfma16(Ah0, WXl[1][it], acc10);
                acc10 = mfma16(Al0, WXh[1][it], acc10);
                acc11 = mfma16(Ah1, WXh[1][it], acc11);
                acc11 = mfma16(Ah1, WXl[1][it], acc11);
                acc11 = mfma16(Al1, WXh[1][it], acc11);
            }
        }

        // wait until all blocks published h_t (t>0). Wave 0 polls all 256 flags.
        if (t > 0) {
            if (tid < 64) {
                const unsigned tgt = (unsigned)t;
                for (;;) {
                    bool ok = true;
                    #pragma unroll
                    for (int i = 0; i < 4; ++i) {
                        unsigned v = __hip_atomic_load(
                            flags + (size_t)(tid + 64 * i) * 16,
                            __ATOMIC_RELAXED, __HIP_MEMORY_SCOPE_AGENT);
                        ok = ok && (v >= tgt);
                    }
                    if (__all(ok)) break;
                    __builtin_amdgcn_s_sleep(2);
                }
                // one acquire load -> invalidate stale L1/L2 before h reads
                unsigned d = __hip_atomic_load(flags, __ATOMIC_ACQUIRE,
                                               __HIP_MEMORY_SCOPE_AGENT);
                asm volatile("" :: "v"(d));
            }
            __syncthreads();
        }

        const unsigned short* hh = hbhi + (size_t)(t & 1) * HB;
        const unsigned short* hl = hblo + (size_t)(t & 1) * HB;
        unsigned short* hh_n = hbhi + (size_t)((t & 1) ^ 1) * HB;
        unsigned short* hl_n = hblo + (size_t)((t & 1) ^ 1) * HB;

        // recurrent term: this wave's K-slice of W_hh
        {
            const unsigned short* ah = hh + lr * H_DIM + 4 * lg;
            const unsigned short* al = hl + lr * H_DIM + 4 * lg;
            const int kb = wv * KHW;
            #pragma unroll
            for (int it = 0; it < ITH; ++it) {
                const int k0 = kb + it * 32;
                bf16x8 Ah0 = load_frag(ah + k0);
                bf16x8 Ah1 = load_frag(ah + 16 * H_DIM + k0);
                bf16x8 Al0 = load_frag(al + k0);
                bf16x8 Al1 = load_frag(al + 16 * H_DIM + k0);
                acc00 = mfma16(Ah0, WHh[0][it], acc00);
                acc00 = mfma16(Ah0, WHl[0][it], acc00);
                acc00 = mfma16(Al0, WHh[0][it], acc00);
                acc01 = mfma16(Ah1, WHh[0][it], acc01);
                acc01 = mfma16(Ah1, WHl[0][it], acc01);
                acc01 = mfma16(Al1, WHh[0][it], acc01);
                acc10 = mfma16(Ah0, WHh[1][it], acc10);
                acc10 = mfma16(Ah0, WHl[1][it], acc10);
                acc10 = mfma16(Al0, WHh[1][it], acc10);
                acc11 = mfma16(Ah1, WHh[1][it], acc11);
                acc11 = mfma16(Ah1, WHl[1][it], acc11);
                acc11 = mfma16(Al1, WHh[1][it], acc11);
            }
        }

        // cross-wave K reduction
        red[wv][0][0][l] = acc00; red[wv][0][1][l] = acc01;
        red[wv][1][0][l] = acc10; red[wv][1][1][l] = acc11;
        __syncthreads();
        #pragma unroll
        for (int o = tid; o < 1024; o += NTHR) {
            int f = o >> 9, m = (o >> 8) & 1, l2 = (o >> 2) & 63, r = o & 3;
            float s = 0.f;
            #pragma unroll
            for (int w = 0; w < 8; ++w) s += red[w][f][m][l2][r];
            int b = 16 * m + 4 * (l2 >> 4) + r;
            int c = l2 & 15;
            int gate = 2 * f + (c >> 3), jl = c & 7;
            gbuf[gate][b][jl] = s + sgl[gate][b][jl];
        }
        __syncthreads();

        // activation: thread<256 owns cell (ab, jb+ajl); c stays in register
        if (tid < 256) {
            float iv = gbuf[0][ab][ajl], fv = gbuf[1][ab][ajl];
            float gv = gbuf[2][ab][ajl], ov = gbuf[3][ab][ajl];
            float cn = sigf(fv) * creg + sigf(iv) * tanhf(gv);
            float hn = sigf(ov) * tanhf(cn);
            creg = cn;
            int j = jb + ajl;
            unsigned short hi = f2bf(hn);
            hh_n[ab * H_DIM + j] = hi;
            hl_n[ab * H_DIM + j] = f2bf(hn - bf2f(hi));
            out[(size_t)t * HB + ab * H_DIM + j] = hn;
        }

        // arrive: publish h_{t+1} with one release-store to our own flag
        if (t < T_DIM - 1) {
            __threadfence();
            __syncthreads();
            if (tid == 0)
                __hip_atomic_store(flags + (size_t)blockIdx.x * 16,
                                   (unsigned)(t + 1), __ATOMIC_RELEASE,
                                   __HIP_MEMORY_SCOPE_AGENT);
        }
    }
}

extern "C" void kernel_launch(void* const* d_in, const int* in_sizes, int n_in,
                              void* d_out, int out_size, void* d_ws, size_t ws_size,
                              hipStream_t stream) {
    const float* embed    = (const float*)d_in[0];
    const float* enc_outs = (const float*)d_in[1];
    const float* h0       = (const float*)d_in[2];
    const float* c0       = (const float*)d_in[3];
    const float* W_ih     = (const float*)d_in[4];
    const float* W_hh     = (const float*)d_in[5];
    const float* b_ih     = (const float*)d_in[6];
    const float* b_hh     = (const float*)d_in[7];
    const int*   tok      = (const int*)d_in[8];
    const int*   langs    = (const int*)d_in[9];
    float* out = (float*)d_out;

    char* ws = (char*)d_ws;
    unsigned short* x_hi = (unsigned short*)(ws + 0);
    unsigned short* x_lo = (unsigned short*)(ws + 4194304);
    unsigned short* hbhi = (unsigned short*)(ws + 8388608);
    unsigned short* hblo = (unsigned short*)(ws + 8650752);
    float* si            = (float*)(ws + 8912896);
    unsigned int* flags  = (unsigned int*)(ws + 9109504);

    hipLaunchKernelGGL(k_prep, dim3(512), dim3(256), 0, stream,
                       enc_outs, embed, langs, h0, si, hbhi, hblo, flags);
    hipLaunchKernelGGL(k_gather_x, dim3(T_DIM * B_DIM), dim3(128), 0, stream,
                       embed, tok, x_hi, x_lo);
    hipLaunchKernelGGL(k_lstm, dim3(NBLK), dim3(NTHR), 0, stream,
                       x_hi, x_lo, hbhi, hblo, si, W_ih, W_hh, b_ih, b_hh, c0,
                       out, flags);
}

// Round 6
// 2692.987 us; speedup vs baseline: 5.1625x; 3.1505x over previous
//
#include <hip/hip_runtime.h>
#include <math.h>

// ---------------- problem dims ----------------
#define E_DIM 512     // embedding dim
#define H_DIM 2048    // hidden
#define G_DIM 8192    // 4*H
#define B_DIM 32      // batch
#define T_DIM 128     // target time
#define S_DIM 128     // source time
#define ENC2  1024    // 2*encoder_hidden
#define SI_DIM 1536   // E + 2*enc (static input)

#define NBLK 256      // persistent blocks (1 per CU)
#define NTHR 512      // 8 waves
#define JT   8        // hidden cols per block
#define KHW  (H_DIM/8)   // 256: W_hh K-slice per wave
#define KXW  (E_DIM/8)   // 64:  W_ih K-slice per wave
#define HB   (B_DIM*H_DIM)   // 65536 elements per h buffer (u32 packed)

// ---------------- workspace layout (bytes) ----------------
// x_hi  bf16 [4096][512]  @ 0        (4194304)
// x_lo  bf16 [4096][512]  @ 4194304  (4194304)
// hp    u32  2x[32][2048] @ 8388608  (524288)   packed h: hi | lo<<16
// si    f32  [32][1536]   @ 8912896  (196608)
// flags u32  [256]x16     @ 9109504  (16384)    64B-strided arrival flags
// total ~9.1 MB

typedef __bf16 bf16_t;
typedef bf16_t bf16x8 __attribute__((ext_vector_type(8)));
typedef float f32x4 __attribute__((ext_vector_type(4)));

__device__ __forceinline__ unsigned short f2bf(float x) {
    unsigned u = __float_as_uint(x);
    u += 0x7FFFu + ((u >> 16) & 1u);   // RNE
    return (unsigned short)(u >> 16);
}
__device__ __forceinline__ float bf2f(unsigned short s) {
    return __uint_as_float(((unsigned)s) << 16);
}
__device__ __forceinline__ unsigned pack2(float a, float b) {
    return (unsigned)f2bf(a) | ((unsigned)f2bf(b) << 16);
}
__device__ __forceinline__ f32x4 mfma16(bf16x8 a, bf16x8 b, f32x4 c) {
    return __builtin_amdgcn_mfma_f32_16x16x32_bf16(a, b, c, 0, 0, 0);
}
__device__ __forceinline__ float sigf(float x) { return 1.f / (1.f + expf(-x)); }

// x fragment load (ordinary cached loads; x is read-only)
__device__ __forceinline__ bf16x8 load_frag(const unsigned short* base) {
    const uint2* p = (const uint2*)base;
    uint2 a = p[0], b = p[4];
    uint4 q; q.x = a.x; q.y = a.y; q.z = b.x; q.w = b.y;
    return __builtin_bit_cast(bf16x8, q);
}

// h fragment pair load from PACKED u32 buffer via agent-scope bypass loads
// (sc1 -> reads coherence point; avoids stale per-XCD L2 without buffer_inv)
__device__ __forceinline__ void lda_pair(const unsigned int* p, bf16x8& Ah, bf16x8& Al) {
    unsigned long long q0 = __hip_atomic_load((const unsigned long long*)(p),
                                              __ATOMIC_RELAXED, __HIP_MEMORY_SCOPE_AGENT);
    unsigned long long q1 = __hip_atomic_load((const unsigned long long*)(p + 2),
                                              __ATOMIC_RELAXED, __HIP_MEMORY_SCOPE_AGENT);
    unsigned long long q2 = __hip_atomic_load((const unsigned long long*)(p + 16),
                                              __ATOMIC_RELAXED, __HIP_MEMORY_SCOPE_AGENT);
    unsigned long long q3 = __hip_atomic_load((const unsigned long long*)(p + 18),
                                              __ATOMIC_RELAXED, __HIP_MEMORY_SCOPE_AGENT);
    unsigned p0 = (unsigned)q0, p1 = (unsigned)(q0 >> 32);
    unsigned p2 = (unsigned)q1, p3 = (unsigned)(q1 >> 32);
    unsigned p4 = (unsigned)q2, p5 = (unsigned)(q2 >> 32);
    unsigned p6 = (unsigned)q3, p7 = (unsigned)(q3 >> 32);
    uint4 h, l;
    h.x = (p0 & 0xFFFFu) | (p1 << 16);
    h.y = (p2 & 0xFFFFu) | (p3 << 16);
    h.z = (p4 & 0xFFFFu) | (p5 << 16);
    h.w = (p6 & 0xFFFFu) | (p7 << 16);
    l.x = (p0 >> 16) | (p1 & 0xFFFF0000u);
    l.y = (p2 >> 16) | (p3 & 0xFFFF0000u);
    l.z = (p4 >> 16) | (p5 & 0xFFFF0000u);
    l.w = (p6 >> 16) | (p7 & 0xFFFF0000u);
    Ah = __builtin_bit_cast(bf16x8, h);
    Al = __builtin_bit_cast(bf16x8, l);
}

// W packing: BY-VALUE return (no address-taken outputs -> SROA keeps regs)
struct WPair { bf16x8 hi, lo; };
__device__ __forceinline__ WPair packW(const float* src) {
    float4 w0 = *(const float4*)src;
    float4 w1 = *(const float4*)(src + 16);
    uint4 qh;
    qh.x = pack2(w0.x, w0.y); qh.y = pack2(w0.z, w0.w);
    qh.z = pack2(w1.x, w1.y); qh.w = pack2(w1.z, w1.w);
    float r0 = w0.x - bf2f((unsigned short)(qh.x & 0xFFFF));
    float r1 = w0.y - bf2f((unsigned short)(qh.x >> 16));
    float r2 = w0.z - bf2f((unsigned short)(qh.y & 0xFFFF));
    float r3 = w0.w - bf2f((unsigned short)(qh.y >> 16));
    float r4 = w1.x - bf2f((unsigned short)(qh.z & 0xFFFF));
    float r5 = w1.y - bf2f((unsigned short)(qh.z >> 16));
    float r6 = w1.z - bf2f((unsigned short)(qh.w & 0xFFFF));
    float r7 = w1.w - bf2f((unsigned short)(qh.w >> 16));
    uint4 ql;
    ql.x = pack2(r0, r1); ql.y = pack2(r2, r3);
    ql.z = pack2(r4, r5); ql.w = pack2(r6, r7);
    WPair out;
    out.hi = __builtin_bit_cast(bf16x8, qh);
    out.lo = __builtin_bit_cast(bf16x8, ql);
    return out;
}

// ---- prep: context max-pool, lang embed, h0 pack, flag reset ----
__global__ void k_prep(const float* __restrict__ enc_outs, const float* __restrict__ embed,
                       const int* __restrict__ langs, const float* __restrict__ h0,
                       float* __restrict__ si, unsigned int* __restrict__ hp,
                       unsigned int* __restrict__ flags) {
    int tid = blockIdx.x * blockDim.x + threadIdx.x;
    int np = gridDim.x * blockDim.x;
    for (int i = tid; i < NBLK * 16; i += np)
        flags[i] = 0u;
    for (int i = tid; i < B_DIM * ENC2; i += np) {        // context = max over S
        int b = i >> 10, e = i & 1023;
        float m = -3.4e38f;
        for (int s = 0; s < S_DIM; ++s)
            m = fmaxf(m, enc_outs[(s * B_DIM + b) * ENC2 + e]);
        si[b * SI_DIM + E_DIM + e] = m;
    }
    for (int i = tid; i < B_DIM * E_DIM; i += np) {       // lang embedding
        int b = i >> 9, e = i & 511;
        si[b * SI_DIM + e] = embed[(long)langs[b] * E_DIM + e];
    }
    for (int i = tid; i < B_DIM * H_DIM; i += np) {       // h0 pack (parity 0)
        float h = h0[i];
        unsigned short hi = f2bf(h);
        unsigned short lo = f2bf(h - bf2f(hi));
        hp[i] = (unsigned)hi | ((unsigned)lo << 16);
    }
}

// ---- gather token embeddings -> x hi/lo [T*B][512], row r = t*32+b ----
__global__ void k_gather_x(const float* __restrict__ embed, const int* __restrict__ tok,
                           unsigned short* __restrict__ xhi, unsigned short* __restrict__ xlo) {
    int r = blockIdx.x;
    int t = r >> 5, b = r & 31;
    long row = tok[b * T_DIM + t];
    const float4* src = (const float4*)(embed + row * E_DIM);
    ushort4* dh = (ushort4*)(xhi + (long)r * E_DIM);
    ushort4* dl = (ushort4*)(xlo + (long)r * E_DIM);
    for (int i = threadIdx.x; i < E_DIM / 4; i += blockDim.x) {
        float4 v = src[i];
        ushort4 h, l;
        h.x = f2bf(v.x); l.x = f2bf(v.x - bf2f(h.x));
        h.y = f2bf(v.y); l.y = f2bf(v.y - bf2f(h.y));
        h.z = f2bf(v.z); l.z = f2bf(v.z - bf2f(h.z));
        h.w = f2bf(v.w); l.w = f2bf(v.w - bf2f(h.w));
        dh[i] = h; dl[i] = l;
    }
}

// per-k-iteration macros over NAMED W fragment variables
#define HH_IT(IT) do { \
    bf16x8 Ah0, Al0, Ah1, Al1; \
    lda_pair(hrow0 + IT * 32, Ah0, Al0); \
    lda_pair(hrow1 + IT * 32, Ah1, Al1); \
    acc00 = mfma16(Ah0, Wh0##IT, acc00); \
    acc00 = mfma16(Ah0, Wl0##IT, acc00); \
    acc00 = mfma16(Al0, Wh0##IT, acc00); \
    acc01 = mfma16(Ah1, Wh0##IT, acc01); \
    acc01 = mfma16(Ah1, Wl0##IT, acc01); \
    acc01 = mfma16(Al1, Wh0##IT, acc01); \
    acc10 = mfma16(Ah0, Wh1##IT, acc10); \
    acc10 = mfma16(Ah0, Wl1##IT, acc10); \
    acc10 = mfma16(Al0, Wh1##IT, acc10); \
    acc11 = mfma16(Ah1, Wh1##IT, acc11); \
    acc11 = mfma16(Ah1, Wl1##IT, acc11); \
    acc11 = mfma16(Al1, Wh1##IT, acc11); \
} while (0)

#define XX_IT(IT) do { \
    bf16x8 Ah0 = load_frag(ax  + IT * 32); \
    bf16x8 Ah1 = load_frag(ax  + 16 * E_DIM + IT * 32); \
    bf16x8 Al0 = load_frag(axl + IT * 32); \
    bf16x8 Al1 = load_frag(axl + 16 * E_DIM + IT * 32); \
    acc00 = mfma16(Ah0, Xh0##IT, acc00); \
    acc00 = mfma16(Ah0, Xl0##IT, acc00); \
    acc00 = mfma16(Al0, Xh0##IT, acc00); \
    acc01 = mfma16(Ah1, Xh0##IT, acc01); \
    acc01 = mfma16(Ah1, Xl0##IT, acc01); \
    acc01 = mfma16(Al1, Xh0##IT, acc01); \
    acc10 = mfma16(Ah0, Xh1##IT, acc10); \
    acc10 = mfma16(Ah0, Xl1##IT, acc10); \
    acc10 = mfma16(Al0, Xh1##IT, acc10); \
    acc11 = mfma16(Ah1, Xh1##IT, acc11); \
    acc11 = mfma16(Ah1, Xl1##IT, acc11); \
    acc11 = mfma16(Al1, Xh1##IT, acc11); \
} while (0)

#define PK_HH(F, IT) { WPair p = packW(W_hh + (long)rowf##F * H_DIM + (wv * KHW + IT * 32 + 4 * lg)); \
                       Wh##F##IT = p.hi; Wl##F##IT = p.lo; }
#define PK_X(F, IT)  { WPair p = packW(W_ih + (long)rowf##F * 2048 + (wv * KXW + IT * 32 + 4 * lg)); \
                       Xh##F##IT = p.hi; Xl##F##IT = p.lo; }

// ---- persistent LSTM: W in named-register frags, fence-free flag barrier ----
__global__ __launch_bounds__(NTHR, 2) void k_lstm(
        const unsigned short* __restrict__ xhi, const unsigned short* __restrict__ xlo,
        unsigned int* __restrict__ hp,
        const float* __restrict__ si, const float* __restrict__ W_ih,
        const float* __restrict__ W_hh, const float* __restrict__ b_ih,
        const float* __restrict__ b_hh, const float* __restrict__ c0,
        float* __restrict__ out, unsigned int* __restrict__ flags) {
    __shared__ f32x4 red[8][2][2][64];     // [wave][frag][Ahalf][lane] partials (32 KB)
    __shared__ float gbuf[4][B_DIM][JT];   // gates (4 KB)
    __shared__ float sgl[4][B_DIM][JT];    // static gate bias (4 KB)

    const int tid = threadIdx.x;
    const int wv = tid >> 6, l = tid & 63, lr = l & 15, lg = l >> 4;
    const int jb = blockIdx.x * JT;

    // ---- prologue 1: static gate bias sg (fp32, block-local) ----
    {
        int c = tid >> 4, bp = tid & 15;        // c: 0..31 gate-col, bp: batch pair base
        int gate = c >> 3, jl = c & 7;
        long grow = (long)(gate * H_DIM + jb + jl);
        const float* wrow = W_ih + grow * 2048 + E_DIM;
        const float* s0 = si + bp * SI_DIM;
        const float* s1 = si + (bp + 16) * SI_DIM;
        float a0 = 0.f, a1 = 0.f;
        for (int k = 0; k < SI_DIM; k += 4) {
            float4 w  = *(const float4*)(wrow + k);
            float4 x0 = *(const float4*)(s0 + k);
            float4 x1 = *(const float4*)(s1 + k);
            a0 += w.x * x0.x + w.y * x0.y + w.z * x0.z + w.w * x0.w;
            a1 += w.x * x1.x + w.y * x1.y + w.z * x1.z + w.w * x1.w;
        }
        float bias = b_ih[grow] + b_hh[grow];
        sgl[gate][bp][jl] = a0 + bias;
        sgl[gate][bp + 16][jl] = a1 + bias;
    }

    // ---- prologue 2: W slices into NAMED register fragments ----
    // frag f covers gate-cols: gate = 2f + (lr>>3), j = jb + (lr&7)
    const int rowf0 = ((lr >> 3)) * H_DIM + jb + (lr & 7);
    const int rowf1 = (2 + (lr >> 3)) * H_DIM + jb + (lr & 7);

    bf16x8 Wh00, Wh01, Wh02, Wh03, Wh04, Wh05, Wh06, Wh07;
    bf16x8 Wh10, Wh11, Wh12, Wh13, Wh14, Wh15, Wh16, Wh17;
    bf16x8 Wl00, Wl01, Wl02, Wl03, Wl04, Wl05, Wl06, Wl07;
    bf16x8 Wl10, Wl11, Wl12, Wl13, Wl14, Wl15, Wl16, Wl17;
    bf16x8 Xh00, Xh01, Xh10, Xh11, Xl00, Xl01, Xl10, Xl11;

    PK_HH(0, 0) PK_HH(0, 1) PK_HH(0, 2) PK_HH(0, 3)
    PK_HH(0, 4) PK_HH(0, 5) PK_HH(0, 6) PK_HH(0, 7)
    PK_HH(1, 0) PK_HH(1, 1) PK_HH(1, 2) PK_HH(1, 3)
    PK_HH(1, 4) PK_HH(1, 5) PK_HH(1, 6) PK_HH(1, 7)
    PK_X(0, 0) PK_X(0, 1) PK_X(1, 0) PK_X(1, 1)

    // ---- prologue 3: cell state in register (thread<256 owns cell (b, jb+jl)) ----
    const int ab = tid >> 3, ajl = tid & 7;     // activation mapping
    float creg = 0.f;
    if (tid < 256) creg = c0[ab * H_DIM + jb + ajl];

    __syncthreads();   // sgl ready

    // ---- time loop ----
    #pragma unroll 1
    for (int t = 0; t < T_DIM; ++t) {
        f32x4 acc00 = {}, acc01 = {}, acc10 = {}, acc11 = {};  // [frag][Ahalf]

        // input term FIRST (independent of h_t; overlaps other blocks' tails)
        {
            const unsigned short* ax  = xhi + (size_t)(t * B_DIM + lr) * E_DIM + 4 * lg + wv * KXW;
            const unsigned short* axl = xlo + (size_t)(t * B_DIM + lr) * E_DIM + 4 * lg + wv * KXW;
            XX_IT(0); XX_IT(1);
        }

        // wait until all blocks published h_t (t>0). Wave 0 polls all 256 flags.
        if (t > 0) {
            if (tid < 64) {
                const unsigned tgt = (unsigned)t;
                for (;;) {
                    bool ok = true;
                    #pragma unroll
                    for (int i = 0; i < 4; ++i) {
                        unsigned v = __hip_atomic_load(
                            flags + (size_t)(tid + 64 * i) * 16,
                            __ATOMIC_RELAXED, __HIP_MEMORY_SCOPE_AGENT);
                        ok = ok && (v >= tgt);
                    }
                    if (__all(ok)) break;
                    __builtin_amdgcn_s_sleep(2);
                }
            }
            __syncthreads();   // h reads below use bypass loads; no cache inv needed
        }

        const unsigned int* hp_cur = hp + (size_t)(t & 1) * HB;
        unsigned int* hp_nxt = hp + (size_t)((t & 1) ^ 1) * HB;

        // recurrent term: this wave's K-slice of W_hh (h via LLC bypass loads)
        {
            const unsigned int* hrow0 = hp_cur + lr * H_DIM + 4 * lg + wv * KHW;
            const unsigned int* hrow1 = hrow0 + 16 * H_DIM;
            HH_IT(0); HH_IT(1); HH_IT(2); HH_IT(3);
            HH_IT(4); HH_IT(5); HH_IT(6); HH_IT(7);
        }

        // cross-wave K reduction
        red[wv][0][0][l] = acc00; red[wv][0][1][l] = acc01;
        red[wv][1][0][l] = acc10; red[wv][1][1][l] = acc11;
        __syncthreads();
        #pragma unroll
        for (int o = tid; o < 1024; o += NTHR) {
            int f = o >> 9, m = (o >> 8) & 1, l2 = (o >> 2) & 63, r = o & 3;
            float s = 0.f;
            #pragma unroll
            for (int w = 0; w < 8; ++w) s += red[w][f][m][l2][r];
            int b = 16 * m + 4 * (l2 >> 4) + r;
            int c = l2 & 15;
            int gate = 2 * f + (c >> 3), jl = c & 7;
            gbuf[gate][b][jl] = s + sgl[gate][b][jl];
        }
        __syncthreads();

        // activation: thread<256 owns cell (ab, jb+ajl); c stays in register.
        // h published as packed u32 write-through (agent scope, no L2 dirty).
        if (tid < 256) {
            float iv = gbuf[0][ab][ajl], fv = gbuf[1][ab][ajl];
            float gv = gbuf[2][ab][ajl], ov = gbuf[3][ab][ajl];
            float cn = sigf(fv) * creg + sigf(iv) * tanhf(gv);
            float hn = sigf(ov) * tanhf(cn);
            creg = cn;
            int j = jb + ajl;
            unsigned short hi = f2bf(hn);
            unsigned short lo = f2bf(hn - bf2f(hi));
            __hip_atomic_store(hp_nxt + ab * H_DIM + j,
                               (unsigned)hi | ((unsigned)lo << 16),
                               __ATOMIC_RELAXED, __HIP_MEMORY_SCOPE_AGENT);
            out[(size_t)t * HB + ab * H_DIM + j] = hn;
        }

        // arrive: drain our stores to the coherence point, then one flag store
        if (t < T_DIM - 1) {
            asm volatile("s_waitcnt vmcnt(0)" ::: "memory");
            __syncthreads();
            if (tid == 0)
                __hip_atomic_store(flags + (size_t)blockIdx.x * 16,
                                   (unsigned)(t + 1), __ATOMIC_RELAXED,
                                   __HIP_MEMORY_SCOPE_AGENT);
        }
    }
}

extern "C" void kernel_launch(void* const* d_in, const int* in_sizes, int n_in,
                              void* d_out, int out_size, void* d_ws, size_t ws_size,
                              hipStream_t stream) {
    const float* embed    = (const float*)d_in[0];
    const float* enc_outs = (const float*)d_in[1];
    const float* h0       = (const float*)d_in[2];
    const float* c0       = (const float*)d_in[3];
    const float* W_ih     = (const float*)d_in[4];
    const float* W_hh     = (const float*)d_in[5];
    const float* b_ih     = (const float*)d_in[6];
    const float* b_hh     = (const float*)d_in[7];
    const int*   tok      = (const int*)d_in[8];
    const int*   langs    = (const int*)d_in[9];
    float* out = (float*)d_out;

    char* ws = (char*)d_ws;
    unsigned short* x_hi = (unsigned short*)(ws + 0);
    unsigned short* x_lo = (unsigned short*)(ws + 4194304);
    unsigned int*   hp   = (unsigned int*)(ws + 8388608);
    float*          si   = (float*)(ws + 8912896);
    unsigned int* flags  = (unsigned int*)(ws + 9109504);

    hipLaunchKernelGGL(k_prep, dim3(512), dim3(256), 0, stream,
                       enc_outs, embed, langs, h0, si, hp, flags);
    hipLaunchKernelGGL(k_gather_x, dim3(T_DIM * B_DIM), dim3(128), 0, stream,
                       embed, tok, x_hi, x_lo);
    hipLaunchKernelGGL(k_lstm, dim3(NBLK), dim3(NTHR), 0, stream,
                       x_hi, x_lo, hp, si, W_ih, W_hh, b_ih, b_hh, c0,
                       out, flags);
}